// Round 5
// baseline (468.104 us; speedup 1.0000x reference)
//
#include <hip/hip_runtime.h>
#include <math.h>

// Quantum conv layer: 4-qubit circuit per 2x2 patch of [64,128,128,1] images.
//
// Math: out_q(patch) = T01^T * C_q * T23, where
//   f_i  = (1, cos(theta_i), sin(theta_i))       (per-pixel, double-angle form)
//   T01  = f_TL (x) f_TR   (9-vec, top pixel pair)
//   T23  = f_BL (x) f_BR   (9-vec, bottom pixel pair)
//   C_q  = 9x9 real tensor derived from the 8 circuit weights (patch-independent).
//
// Two kernels: tiny setup (builds C_q in d_ws) + main (patch evaluation).
// Setup is separate so the main kernel stays register-lean (fused version
// measured 184 VGPR -> 10.8% occupancy, 102 us).

#define HO 127
#define WO 127
#define HH 128
#define WW 128
#define TILE_W 16
#define TILE_H 32   // patch rows per block (2 per thread, vertical pair)

// -------------------- setup: weights -> C[4][9][12] in ws --------------------
__global__ __launch_bounds__(256) void qconv_setup(
    const float* __restrict__ weights, float* __restrict__ Cws)
{
    __shared__ float Ur[16][16], Ui[16][16];   // U[s][t], col t = circuit on |t>
    __shared__ float A[4][16][16];             // A_q[t][t'] = Re(U^H Z_q U)
    const int tid = threadIdx.x;

    // phase 1: threads 0..15 each simulate one basis column through the circuit
    if (tid < 16) {
        float sr[16], si[16];
        #pragma unroll
        for (int s = 0; s < 16; ++s) { sr[s] = 0.f; si[s] = 0.f; }
        sr[tid] = 1.f;
        for (int l = 0; l < 2; ++l) {
            // RX(w[l][q]) on each qubit (qubit 0 = MSB of state index)
            for (int q = 0; q < 4; ++q) {
                float w  = weights[l*4 + q];
                float ch = cosf(0.5f*w), sh = sinf(0.5f*w);
                const int bit = 1 << (3 - q);
                for (int s0 = 0; s0 < 16; ++s0) {
                    if (s0 & bit) continue;
                    const int s1 = s0 | bit;
                    float a0r = sr[s0], a0i = si[s0];
                    float a1r = sr[s1], a1i = si[s1];
                    sr[s0] = fmaf(ch, a0r,  sh*a1i);   // c*a0 - i*s*a1
                    si[s0] = fmaf(ch, a0i, -sh*a1r);
                    sr[s1] = fmaf(ch, a1r,  sh*a0i);   // -i*s*a0 + c*a1
                    si[s1] = fmaf(ch, a1i, -sh*a0r);
                }
            }
            // CNOT ring q -> (q+1)%4
            for (int q = 0; q < 4; ++q) {
                const int bc = 1 << (3 - q), bt = 1 << (3 - ((q+1)&3));
                for (int s0 = 0; s0 < 16; ++s0) {
                    if ((s0 & bc) && !(s0 & bt)) {
                        const int s1 = s0 | bt;
                        float tr = sr[s0], ti = si[s0];
                        sr[s0] = sr[s1]; si[s0] = si[s1];
                        sr[s1] = tr;     si[s1] = ti;
                    }
                }
            }
        }
        #pragma unroll
        for (int s = 0; s < 16; ++s) { Ur[s][tid] = sr[s]; Ui[s][tid] = si[s]; }
    }
    __syncthreads();

    // phase 2: A_q[t][t'] = sum_s sign_q(s) * Re(conj(U[s,t]) U[s,t'])
    for (int e = tid; e < 1024; e += 256) {
        int q = e >> 8, t = (e >> 4) & 15, tp = e & 15;
        float acc = 0.f;
        #pragma unroll
        for (int s = 0; s < 16; ++s) {
            float d = Ur[s][t]*Ur[s][tp] + Ui[s][t]*Ui[s][tp];
            acc += ((s >> (3 - q)) & 1) ? -d : d;
        }
        A[q][t][tp] = acc;
    }
    __syncthreads();

    // phase 3: coefficient tensor. For k in {0,1,2}^4 the (t,t') double sum
    // collapses: t' = t ^ mask(k_i==2), weight = (1/16)*prod_{k_i==1}(1-2 t_i)
    for (int e = tid; e < 324; e += 256) {     // grid-stride: 324 > 256!
        int q = e / 81, kk = e % 81;
        int k0 = kk/27, k1 = (kk/9)%3, k2 = (kk/3)%3, k3 = kk%3;
        int mask = 0, sb = 0;
        if (k0 == 2) mask |= 8; else if (k0 == 1) sb |= 8;
        if (k1 == 2) mask |= 4; else if (k1 == 1) sb |= 4;
        if (k2 == 2) mask |= 2; else if (k2 == 1) sb |= 2;
        if (k3 == 2) mask |= 1; else if (k3 == 1) sb |= 1;
        float acc = 0.f;
        #pragma unroll
        for (int t = 0; t < 16; ++t) {
            float a = A[q][t][t ^ mask];
            acc += (__popc(t & sb) & 1) ? -a : a;
        }
        Cws[(q*9 + (k0*3 + k1))*12 + (k2*3 + k3)] = acc * 0.0625f;
    }
}

// -------------------- main: patches -> expectation values --------------------
__global__ __launch_bounds__(256, 4) void qconv_main(
    const float* __restrict__ images, const float* __restrict__ Cws,
    float* __restrict__ out)
{
    __shared__ float  C[4][9][12];    // padded rows -> 16B-aligned b128 reads
    __shared__ float2 px[33][17];     // (cos, sin) per staged pixel

    const int tid = threadIdx.x;

    // coefficients: 432 floats = 108 float4 (broadcast-read later)
    if (tid < 108)
        reinterpret_cast<float4*>(&C[0][0][0])[tid] =
            reinterpret_cast<const float4*>(Cws)[tid];

    const int x0 = blockIdx.x * TILE_W;
    const int y0 = blockIdx.y * TILE_H;
    const int b  = blockIdx.z;
    const float* img = images + (size_t)b * (HH*WW);

    // stage tile pixels; hardware trig (theta in [0,pi), no range reduction
    // needed; |err| ~ 1e-6 vs 2e-3 observed absmax margin)
    for (int idx = tid; idx < 33*17; idx += 256) {
        int py = idx / 17, pc = idx - py*17;
        int gy = min(y0 + py, HH - 1);
        int gx = min(x0 + pc, WW - 1);
        float th = img[gy*WW + gx];
        float sn, cs;
        __sincosf(th, &sn, &cs);
        px[py][pc] = make_float2(cs, sn);
    }
    __syncthreads();

    const int tx = tid & 15, ty = tid >> 4;
    const int c  = x0 + tx;
    const int rA = y0 + 2*ty;          // patch A row; patch B = rA+1

    // three horizontal pixel-pair vectors (rows 2ty, 2ty+1, 2ty+2);
    // middle one shared: t23(A) == t01(B)
    float2 p0L = px[2*ty  ][tx], p0R = px[2*ty  ][tx+1];
    float2 p1L = px[2*ty+1][tx], p1R = px[2*ty+1][tx+1];
    float2 p2L = px[2*ty+2][tx], p2R = px[2*ty+2][tx+1];

    float T0[9], T1[9], T2[9];
    T0[0]=1.f;   T0[1]=p0R.x;       T0[2]=p0R.y;
    T0[3]=p0L.x; T0[4]=p0L.x*p0R.x; T0[5]=p0L.x*p0R.y;
    T0[6]=p0L.y; T0[7]=p0L.y*p0R.x; T0[8]=p0L.y*p0R.y;
    T1[0]=1.f;   T1[1]=p1R.x;       T1[2]=p1R.y;
    T1[3]=p1L.x; T1[4]=p1L.x*p1R.x; T1[5]=p1L.x*p1R.y;
    T1[6]=p1L.y; T1[7]=p1L.y*p1R.x; T1[8]=p1L.y*p1R.y;
    T2[0]=1.f;   T2[1]=p2R.x;       T2[2]=p2R.y;
    T2[3]=p2L.x; T2[4]=p2L.x*p2R.x; T2[5]=p2L.x*p2R.y;
    T2[6]=p2L.y; T2[7]=p2L.y*p2R.x; T2[8]=p2L.y*p2R.y;

    float oA[4], oB[4];
    #pragma unroll
    for (int q = 0; q < 4; ++q) {
        float accA = 0.f, accB = 0.f;
        #pragma unroll
        for (int i = 0; i < 9; ++i) {
            const float* row = &C[q][i][0];
            float4 ra = *reinterpret_cast<const float4*>(row);      // broadcast
            float4 rb = *reinterpret_cast<const float4*>(row + 4);
            float  r8 = row[8];
            float dA = ra.x, dB = ra.x;                 // T[0] == 1
            dA = fmaf(ra.y, T1[1], dA);  dB = fmaf(ra.y, T2[1], dB);
            dA = fmaf(ra.z, T1[2], dA);  dB = fmaf(ra.z, T2[2], dB);
            dA = fmaf(ra.w, T1[3], dA);  dB = fmaf(ra.w, T2[3], dB);
            dA = fmaf(rb.x, T1[4], dA);  dB = fmaf(rb.x, T2[4], dB);
            dA = fmaf(rb.y, T1[5], dA);  dB = fmaf(rb.y, T2[5], dB);
            dA = fmaf(rb.z, T1[6], dA);  dB = fmaf(rb.z, T2[6], dB);
            dA = fmaf(rb.w, T1[7], dA);  dB = fmaf(rb.w, T2[7], dB);
            dA = fmaf(r8,   T1[8], dA);  dB = fmaf(r8,   T2[8], dB);
            accA = fmaf(T0[i], dA, accA);
            accB = fmaf(T1[i], dB, accB);
        }
        oA[q] = accA; oB[q] = accB;
    }

    if (c < WO) {
        if (rA < HO)
            *reinterpret_cast<float4*>(out + ((size_t)((size_t)b*HO + rA)*WO + c)*4) =
                make_float4(oA[0], oA[1], oA[2], oA[3]);
        if (rA + 1 < HO)
            *reinterpret_cast<float4*>(out + ((size_t)((size_t)b*HO + rA+1)*WO + c)*4) =
                make_float4(oB[0], oB[1], oB[2], oB[3]);
    }
}

extern "C" void kernel_launch(void* const* d_in, const int* in_sizes, int n_in,
                              void* d_out, int out_size, void* d_ws, size_t ws_size,
                              hipStream_t stream) {
    const float* images  = (const float*)d_in[0];   // [64,128,128,1]
    const float* weights = (const float*)d_in[1];   // [2,4]
    float* outp = (float*)d_out;                    // [64,127,127,4]
    float* Cws  = (float*)d_ws;                     // 432 floats used

    qconv_setup<<<dim3(1,1,1), dim3(256,1,1), 0, stream>>>(weights, Cws);

    dim3 grid((WO + TILE_W - 1)/TILE_W,   // 8
              (HO + TILE_H - 1)/TILE_H,   // 4
              64);
    qconv_main<<<grid, dim3(256,1,1), 0, stream>>>(images, Cws, outp);
}

// Round 7
// 96.261 us; speedup vs baseline: 4.8629x; 4.8629x over previous
//
#include <hip/hip_runtime.h>
#include <math.h>

// Quantum conv layer: 4-qubit circuit per 2x2 patch of [64,128,128,1] images.
//
// Math: out_q(patch) = T01^T * C_q * T23, where
//   f_i  = (1, cos(theta_i), sin(theta_i))       (per-pixel, double-angle form)
//   T01  = f_TL (x) f_TR   (9-vec, top pixel pair)
//   T23  = f_BL (x) f_BR   (9-vec, bottom pixel pair)
//   C_q  = 9x9 real tensor derived from the 8 circuit weights (patch-independent).
//
// Two kernels: tiny setup (builds C_q in d_ws) + main (patch evaluation).
//
// HISTORY (measured):
//  - fused setup+main: 184 VGPR, occ 10.8%, VALUBusy 22%, 102 us (libm sincos
//    + per-block setup bloat).
//  - split + __sincosf + __launch_bounds__(256,4): compiler took a 64-VGPR /
//    8-waves-per-EU budget and spilled ~300 dwords/thread -> 1.3 GB scratch
//    HBM round-trip, 420 us, VALUBusy 2%. NEVER floor occupancy here; the
//    unrolled 36-FMA body needs ~100 VGPRs in registers.

#define HO 127
#define WO 127
#define HH 128
#define WW 128
#define TILE_W 16
#define TILE_H 32   // patch rows per block (2 per thread, vertical pair)

// -------------------- setup: weights -> C[4][9][12] in ws --------------------
__global__ __launch_bounds__(256) void qconv_setup(
    const float* __restrict__ weights, float* __restrict__ Cws)
{
    __shared__ float Ur[16][16], Ui[16][16];   // U[s][t], col t = circuit on |t>
    __shared__ float A[4][16][16];             // A_q[t][t'] = Re(U^H Z_q U)
    const int tid = threadIdx.x;

    // phase 1: threads 0..15 each simulate one basis column through the circuit
    if (tid < 16) {
        float sr[16], si[16];
        #pragma unroll
        for (int s = 0; s < 16; ++s) { sr[s] = 0.f; si[s] = 0.f; }
        sr[tid] = 1.f;
        for (int l = 0; l < 2; ++l) {
            // RX(w[l][q]) on each qubit (qubit 0 = MSB of state index)
            for (int q = 0; q < 4; ++q) {
                float w  = weights[l*4 + q];
                float ch = cosf(0.5f*w), sh = sinf(0.5f*w);
                const int bit = 1 << (3 - q);
                for (int s0 = 0; s0 < 16; ++s0) {
                    if (s0 & bit) continue;
                    const int s1 = s0 | bit;
                    float a0r = sr[s0], a0i = si[s0];
                    float a1r = sr[s1], a1i = si[s1];
                    sr[s0] = fmaf(ch, a0r,  sh*a1i);   // c*a0 - i*s*a1
                    si[s0] = fmaf(ch, a0i, -sh*a1r);
                    sr[s1] = fmaf(ch, a1r,  sh*a0i);   // -i*s*a0 + c*a1
                    si[s1] = fmaf(ch, a1i, -sh*a0r);
                }
            }
            // CNOT ring q -> (q+1)%4
            for (int q = 0; q < 4; ++q) {
                const int bc = 1 << (3 - q), bt = 1 << (3 - ((q+1)&3));
                for (int s0 = 0; s0 < 16; ++s0) {
                    if ((s0 & bc) && !(s0 & bt)) {
                        const int s1 = s0 | bt;
                        float tr = sr[s0], ti = si[s0];
                        sr[s0] = sr[s1]; si[s0] = si[s1];
                        sr[s1] = tr;     si[s1] = ti;
                    }
                }
            }
        }
        #pragma unroll
        for (int s = 0; s < 16; ++s) { Ur[s][tid] = sr[s]; Ui[s][tid] = si[s]; }
    }
    __syncthreads();

    // phase 2: A_q[t][t'] = sum_s sign_q(s) * Re(conj(U[s,t]) U[s,t'])
    for (int e = tid; e < 1024; e += 256) {
        int q = e >> 8, t = (e >> 4) & 15, tp = e & 15;
        float acc = 0.f;
        #pragma unroll
        for (int s = 0; s < 16; ++s) {
            float d = Ur[s][t]*Ur[s][tp] + Ui[s][t]*Ui[s][tp];
            acc += ((s >> (3 - q)) & 1) ? -d : d;
        }
        A[q][t][tp] = acc;
    }
    __syncthreads();

    // phase 3: coefficient tensor. For k in {0,1,2}^4 the (t,t') double sum
    // collapses: t' = t ^ mask(k_i==2), weight = (1/16)*prod_{k_i==1}(1-2 t_i)
    for (int e = tid; e < 324; e += 256) {     // grid-stride: 324 > 256!
        int q = e / 81, kk = e % 81;
        int k0 = kk/27, k1 = (kk/9)%3, k2 = (kk/3)%3, k3 = kk%3;
        int mask = 0, sb = 0;
        if (k0 == 2) mask |= 8; else if (k0 == 1) sb |= 8;
        if (k1 == 2) mask |= 4; else if (k1 == 1) sb |= 4;
        if (k2 == 2) mask |= 2; else if (k2 == 1) sb |= 2;
        if (k3 == 2) mask |= 1; else if (k3 == 1) sb |= 1;
        float acc = 0.f;
        #pragma unroll
        for (int t = 0; t < 16; ++t) {
            float a = A[q][t][t ^ mask];
            acc += (__popc(t & sb) & 1) ? -a : a;
        }
        Cws[(q*9 + (k0*3 + k1))*12 + (k2*3 + k3)] = acc * 0.0625f;
    }
}

// -------------------- main: patches -> expectation values --------------------
__global__ __launch_bounds__(256) void qconv_main(
    const float* __restrict__ images, const float* __restrict__ Cws,
    float* __restrict__ out)
{
    __shared__ float  C[4][9][12];    // padded rows -> 16B-aligned b128 reads
    __shared__ float2 px[33][17];     // (cos, sin) per staged pixel

    const int tid = threadIdx.x;

    // coefficients: 432 floats = 108 float4 (broadcast-read later)
    if (tid < 108)
        reinterpret_cast<float4*>(&C[0][0][0])[tid] =
            reinterpret_cast<const float4*>(Cws)[tid];

    const int x0 = blockIdx.x * TILE_W;
    const int y0 = blockIdx.y * TILE_H;
    const int b  = blockIdx.z;
    const float* img = images + (size_t)b * (HH*WW);

    // stage tile pixels; hardware trig (theta in [0,pi), no range reduction
    // needed; |err| ~ 1e-6 vs 2e-3 observed absmax margin)
    for (int idx = tid; idx < 33*17; idx += 256) {
        int py = idx / 17, pc = idx - py*17;
        int gy = min(y0 + py, HH - 1);
        int gx = min(x0 + pc, WW - 1);
        float th = img[gy*WW + gx];
        float sn, cs;
        __sincosf(th, &sn, &cs);
        px[py][pc] = make_float2(cs, sn);
    }
    __syncthreads();

    const int tx = tid & 15, ty = tid >> 4;
    const int c  = x0 + tx;
    const int rA = y0 + 2*ty;          // patch A row; patch B = rA+1

    // three horizontal pixel-pair vectors (rows 2ty, 2ty+1, 2ty+2);
    // middle one shared: t23(A) == t01(B)
    float2 p0L = px[2*ty  ][tx], p0R = px[2*ty  ][tx+1];
    float2 p1L = px[2*ty+1][tx], p1R = px[2*ty+1][tx+1];
    float2 p2L = px[2*ty+2][tx], p2R = px[2*ty+2][tx+1];

    float T0[9], T1[9], T2[9];
    T0[0]=1.f;   T0[1]=p0R.x;       T0[2]=p0R.y;
    T0[3]=p0L.x; T0[4]=p0L.x*p0R.x; T0[5]=p0L.x*p0R.y;
    T0[6]=p0L.y; T0[7]=p0L.y*p0R.x; T0[8]=p0L.y*p0R.y;
    T1[0]=1.f;   T1[1]=p1R.x;       T1[2]=p1R.y;
    T1[3]=p1L.x; T1[4]=p1L.x*p1R.x; T1[5]=p1L.x*p1R.y;
    T1[6]=p1L.y; T1[7]=p1L.y*p1R.x; T1[8]=p1L.y*p1R.y;
    T2[0]=1.f;   T2[1]=p2R.x;       T2[2]=p2R.y;
    T2[3]=p2L.x; T2[4]=p2L.x*p2R.x; T2[5]=p2L.x*p2R.y;
    T2[6]=p2L.y; T2[7]=p2L.y*p2R.x; T2[8]=p2L.y*p2R.y;

    float oA[4], oB[4];
    #pragma unroll
    for (int q = 0; q < 4; ++q) {
        float accA = 0.f, accB = 0.f;
        #pragma unroll
        for (int i = 0; i < 9; ++i) {
            const float* row = &C[q][i][0];
            float4 ra = *reinterpret_cast<const float4*>(row);      // broadcast
            float4 rb = *reinterpret_cast<const float4*>(row + 4);
            float  r8 = row[8];
            float dA = ra.x, dB = ra.x;                 // T[0] == 1
            dA = fmaf(ra.y, T1[1], dA);  dB = fmaf(ra.y, T2[1], dB);
            dA = fmaf(ra.z, T1[2], dA);  dB = fmaf(ra.z, T2[2], dB);
            dA = fmaf(ra.w, T1[3], dA);  dB = fmaf(ra.w, T2[3], dB);
            dA = fmaf(rb.x, T1[4], dA);  dB = fmaf(rb.x, T2[4], dB);
            dA = fmaf(rb.y, T1[5], dA);  dB = fmaf(rb.y, T2[5], dB);
            dA = fmaf(rb.z, T1[6], dA);  dB = fmaf(rb.z, T2[6], dB);
            dA = fmaf(rb.w, T1[7], dA);  dB = fmaf(rb.w, T2[7], dB);
            dA = fmaf(r8,   T1[8], dA);  dB = fmaf(r8,   T2[8], dB);
            accA = fmaf(T0[i], dA, accA);
            accB = fmaf(T1[i], dB, accB);
        }
        oA[q] = accA; oB[q] = accB;
    }

    if (c < WO) {
        if (rA < HO)
            *reinterpret_cast<float4*>(out + ((size_t)((size_t)b*HO + rA)*WO + c)*4) =
                make_float4(oA[0], oA[1], oA[2], oA[3]);
        if (rA + 1 < HO)
            *reinterpret_cast<float4*>(out + ((size_t)((size_t)b*HO + rA+1)*WO + c)*4) =
                make_float4(oB[0], oB[1], oB[2], oB[3]);
    }
}

extern "C" void kernel_launch(void* const* d_in, const int* in_sizes, int n_in,
                              void* d_out, int out_size, void* d_ws, size_t ws_size,
                              hipStream_t stream) {
    const float* images  = (const float*)d_in[0];   // [64,128,128,1]
    const float* weights = (const float*)d_in[1];   // [2,4]
    float* outp = (float*)d_out;                    // [64,127,127,4]
    float* Cws  = (float*)d_ws;                     // 432 floats used

    qconv_setup<<<dim3(1,1,1), dim3(256,1,1), 0, stream>>>(weights, Cws);

    dim3 grid((WO + TILE_W - 1)/TILE_W,   // 8
              (HO + TILE_H - 1)/TILE_H,   // 4
              64);
    qconv_main<<<grid, dim3(256,1,1), 0, stream>>>(images, Cws, outp);
}

// Round 8
// 95.382 us; speedup vs baseline: 4.9077x; 1.0092x over previous
//
#include <hip/hip_runtime.h>
#include <math.h>

// Quantum conv layer: 4-qubit circuit per 2x2 patch of [64,128,128,1] images.
//
// Math: out_q(patch) = T01^T * C_q * T23, where
//   f_i  = (1, cos(theta_i), sin(theta_i))       (per-pixel, double-angle form)
//   T01  = f_TL (x) f_TR   (9-vec, top pixel pair)
//   T23  = f_BL (x) f_BR   (9-vec, bottom pixel pair)
//   C_q  = 9x9 real tensor derived from the 8 circuit weights (patch-independent).
//
// Two kernels: tiny setup (builds C_q in d_ws) + main (patch evaluation).
//
// HISTORY (measured on MI355X):
//  - fused setup+main: 184 VGPR, occ 10.8%, VALUBusy 22%, 102 us.
//  - split + __launch_bounds__(256,4): compiler took 64 VGPR -> ~300 dw/thread
//    scratch spill -> 1.3 GB HBM round-trip, 420 us, VALUBusy 2%. Empirical
//    mapping of the 2nd launch_bounds arg is NOT waves/EU=4; avoid it.
//  - split + plain (256): 184 VGPR again (allocator bloat, not setup), occ
//    9.1%, VALUBusy 26.5%, FETCH/WRITE ideal (5.7/17.1 MB), main = 41.9 us.
//    Bottleneck arithmetic: 108 LDS C-row reads/thread ~ 17 us/CU of ds_read
//    issue > 10 us FMA stream -> LDS-issue-bound at 2 blocks/CU.
//  - THIS version: C read via uniform compile-time-indexed loads from global
//    (scalarizes to s_load -> SGPR operands in v_fma; all C LDS traffic
//    deleted) + amdgpu_waves_per_eu(4) caps VGPR at 128 (4 blocks/CU).

#define HO 127
#define WO 127
#define HH 128
#define WW 128
#define TILE_W 16
#define TILE_H 32   // patch rows per block (2 per thread, vertical pair)

// -------------------- setup: weights -> C[4][9][12] in ws --------------------
__global__ __launch_bounds__(256) void qconv_setup(
    const float* __restrict__ weights, float* __restrict__ Cws)
{
    __shared__ float Ur[16][16], Ui[16][16];   // U[s][t], col t = circuit on |t>
    __shared__ float A[4][16][16];             // A_q[t][t'] = Re(U^H Z_q U)
    const int tid = threadIdx.x;

    // phase 1: threads 0..15 each simulate one basis column through the circuit
    if (tid < 16) {
        float sr[16], si[16];
        #pragma unroll
        for (int s = 0; s < 16; ++s) { sr[s] = 0.f; si[s] = 0.f; }
        sr[tid] = 1.f;
        for (int l = 0; l < 2; ++l) {
            // RX(w[l][q]) on each qubit (qubit 0 = MSB of state index)
            for (int q = 0; q < 4; ++q) {
                float w  = weights[l*4 + q];
                float ch = cosf(0.5f*w), sh = sinf(0.5f*w);
                const int bit = 1 << (3 - q);
                for (int s0 = 0; s0 < 16; ++s0) {
                    if (s0 & bit) continue;
                    const int s1 = s0 | bit;
                    float a0r = sr[s0], a0i = si[s0];
                    float a1r = sr[s1], a1i = si[s1];
                    sr[s0] = fmaf(ch, a0r,  sh*a1i);   // c*a0 - i*s*a1
                    si[s0] = fmaf(ch, a0i, -sh*a1r);
                    sr[s1] = fmaf(ch, a1r,  sh*a0i);   // -i*s*a0 + c*a1
                    si[s1] = fmaf(ch, a1i, -sh*a0r);
                }
            }
            // CNOT ring q -> (q+1)%4
            for (int q = 0; q < 4; ++q) {
                const int bc = 1 << (3 - q), bt = 1 << (3 - ((q+1)&3));
                for (int s0 = 0; s0 < 16; ++s0) {
                    if ((s0 & bc) && !(s0 & bt)) {
                        const int s1 = s0 | bt;
                        float tr = sr[s0], ti = si[s0];
                        sr[s0] = sr[s1]; si[s0] = si[s1];
                        sr[s1] = tr;     si[s1] = ti;
                    }
                }
            }
        }
        #pragma unroll
        for (int s = 0; s < 16; ++s) { Ur[s][tid] = sr[s]; Ui[s][tid] = si[s]; }
    }
    __syncthreads();

    // phase 2: A_q[t][t'] = sum_s sign_q(s) * Re(conj(U[s,t]) U[s,t'])
    for (int e = tid; e < 1024; e += 256) {
        int q = e >> 8, t = (e >> 4) & 15, tp = e & 15;
        float acc = 0.f;
        #pragma unroll
        for (int s = 0; s < 16; ++s) {
            float d = Ur[s][t]*Ur[s][tp] + Ui[s][t]*Ui[s][tp];
            acc += ((s >> (3 - q)) & 1) ? -d : d;
        }
        A[q][t][tp] = acc;
    }
    __syncthreads();

    // phase 3: coefficient tensor. For k in {0,1,2}^4 the (t,t') double sum
    // collapses: t' = t ^ mask(k_i==2), weight = (1/16)*prod_{k_i==1}(1-2 t_i)
    for (int e = tid; e < 324; e += 256) {     // grid-stride: 324 > 256!
        int q = e / 81, kk = e % 81;
        int k0 = kk/27, k1 = (kk/9)%3, k2 = (kk/3)%3, k3 = kk%3;
        int mask = 0, sb = 0;
        if (k0 == 2) mask |= 8; else if (k0 == 1) sb |= 8;
        if (k1 == 2) mask |= 4; else if (k1 == 1) sb |= 4;
        if (k2 == 2) mask |= 2; else if (k2 == 1) sb |= 2;
        if (k3 == 2) mask |= 1; else if (k3 == 1) sb |= 1;
        float acc = 0.f;
        #pragma unroll
        for (int t = 0; t < 16; ++t) {
            float a = A[q][t][t ^ mask];
            acc += (__popc(t & sb) & 1) ? -a : a;
        }
        Cws[(q*9 + (k0*3 + k1))*12 + (k2*3 + k3)] = acc * 0.0625f;
    }
}

// -------------------- main: patches -> expectation values --------------------
__global__ __launch_bounds__(256)
__attribute__((amdgpu_waves_per_eu(4)))       // cap VGPR at 128 -> 4 blocks/CU
void qconv_main(
    const float* __restrict__ images, const float* __restrict__ Cws,
    float* __restrict__ out)
{
    __shared__ float2 px[33][17];     // (cos, sin) per staged pixel

    const int tid = threadIdx.x;
    const int x0 = blockIdx.x * TILE_W;
    const int y0 = blockIdx.y * TILE_H;
    const int b  = blockIdx.z;
    const float* img = images + (size_t)b * (HH*WW);

    // stage tile pixels; hardware trig (theta in [0,pi), no range reduction
    // needed; |err| ~ 1e-6 vs 2e-3 observed absmax margin)
    for (int idx = tid; idx < 33*17; idx += 256) {
        int py = idx / 17, pc = idx - py*17;
        int gy = min(y0 + py, HH - 1);
        int gx = min(x0 + pc, WW - 1);
        float th = img[gy*WW + gx];
        float sn, cs;
        __sincosf(th, &sn, &cs);
        px[py][pc] = make_float2(cs, sn);
    }
    __syncthreads();

    const int tx = tid & 15, ty = tid >> 4;
    const int c  = x0 + tx;
    const int rA = y0 + 2*ty;          // patch A row; patch B = rA+1

    // three horizontal pixel-pair vectors (rows 2ty, 2ty+1, 2ty+2);
    // middle one shared: t23(A) == t01(B)
    float2 p0L = px[2*ty  ][tx], p0R = px[2*ty  ][tx+1];
    float2 p1L = px[2*ty+1][tx], p1R = px[2*ty+1][tx+1];
    float2 p2L = px[2*ty+2][tx], p2R = px[2*ty+2][tx+1];

    float T0[9], T1[9], T2[9];
    T0[0]=1.f;   T0[1]=p0R.x;       T0[2]=p0R.y;
    T0[3]=p0L.x; T0[4]=p0L.x*p0R.x; T0[5]=p0L.x*p0R.y;
    T0[6]=p0L.y; T0[7]=p0L.y*p0R.x; T0[8]=p0L.y*p0R.y;
    T1[0]=1.f;   T1[1]=p1R.x;       T1[2]=p1R.y;
    T1[3]=p1L.x; T1[4]=p1L.x*p1R.x; T1[5]=p1L.x*p1R.y;
    T1[6]=p1L.y; T1[7]=p1L.y*p1R.x; T1[8]=p1L.y*p1R.y;
    T2[0]=1.f;   T2[1]=p2R.x;       T2[2]=p2R.y;
    T2[3]=p2L.x; T2[4]=p2L.x*p2R.x; T2[5]=p2L.x*p2R.y;
    T2[6]=p2L.y; T2[7]=p2L.y*p2R.x; T2[8]=p2L.y*p2R.y;

    // C reads: block-uniform pointer + compile-time offsets -> the compiler
    // scalarizes these to s_load; each v_fma below then uses one SGPR operand.
    // No LDS, no per-lane VGPR copies of C.
    float oA[4], oB[4];
    #pragma unroll
    for (int q = 0; q < 4; ++q) {
        float accA = 0.f, accB = 0.f;
        #pragma unroll
        for (int i = 0; i < 9; ++i) {
            const float* row = Cws + (q*9 + i)*12;
            float dA = row[0], dB = row[0];             // T[0] == 1
            #pragma unroll
            for (int j = 1; j < 9; ++j) {
                dA = fmaf(row[j], T1[j], dA);
                dB = fmaf(row[j], T2[j], dB);
            }
            accA = fmaf(T0[i], dA, accA);
            accB = fmaf(T1[i], dB, accB);
        }
        oA[q] = accA; oB[q] = accB;
    }

    if (c < WO) {
        if (rA < HO)
            *reinterpret_cast<float4*>(out + ((size_t)((size_t)b*HO + rA)*WO + c)*4) =
                make_float4(oA[0], oA[1], oA[2], oA[3]);
        if (rA + 1 < HO)
            *reinterpret_cast<float4*>(out + ((size_t)((size_t)b*HO + rA+1)*WO + c)*4) =
                make_float4(oB[0], oB[1], oB[2], oB[3]);
    }
}

extern "C" void kernel_launch(void* const* d_in, const int* in_sizes, int n_in,
                              void* d_out, int out_size, void* d_ws, size_t ws_size,
                              hipStream_t stream) {
    const float* images  = (const float*)d_in[0];   // [64,128,128,1]
    const float* weights = (const float*)d_in[1];   // [2,4]
    float* outp = (float*)d_out;                    // [64,127,127,4]
    float* Cws  = (float*)d_ws;                     // 432 floats used

    qconv_setup<<<dim3(1,1,1), dim3(256,1,1), 0, stream>>>(weights, Cws);

    dim3 grid((WO + TILE_W - 1)/TILE_W,   // 8
              (HO + TILE_H - 1)/TILE_H,   // 4
              64);
    qconv_main<<<grid, dim3(256,1,1), 0, stream>>>(images, Cws, outp);
}